// Round 10
// baseline (115.688 us; speedup 1.0000x reference)
//
#include <hip/hip_runtime.h>

// NeighborList: N atoms, minimum-image convention, cutoff 5.0.
// Output layout (all float32): pairs[2*P], deltas[P*3], distances[P], n_pairs[1]
// Ordering must match jnp.nonzero(mask.ravel()) -> ascending flat index i*N+j.
//
// FOUR dispatches. Hard-won structure notes:
//  - NO intra-kernel global sync: cg grid.sync = 140us (R3), hand-rolled
//    acquire/release spin = 535us (R8) on this 8-XCD chip.
//  - Only WORK REDUCTION has ever improved dur (R6 diag path -8us); occupancy,
//    balance, LDS staging, SoA all neutral. This round: cell-list pruning,
//    8.4M -> ~1.3M pair tests. Masks make it order-safe: hit bits are set via
//    idempotent atomicOr, counts via ballot popcount, K2's ordered fill is
//    unchanged -> output bit-identical to the O(N^2) path.
//  - K0a: pad out + zero masks + AoS->SoA. Kbuild: single-block counting sort
//    into cells (cell-sorted coord copies -> contiguous candidate loads).
//  - K1: per-row count over 27 neighbor cells (fallback: O(N^2) scan when box
//    is non-diagonal or grid < 3 cells/dim). K2: int4 prefix + ordered fill.

#define CUT2 25.0f
#define CUTOFF 5.0f
#define MAXC 512   // max total cells kept in LDS histogram

__device__ __forceinline__ void load_box_inv(const float* __restrict__ box,
                                             float B[3][3], float Binv[3][3]) {
    #pragma unroll
    for (int r = 0; r < 3; ++r)
        #pragma unroll
        for (int c = 0; c < 3; ++c)
            B[r][c] = box[r * 3 + c];

    float a00 = B[0][0], a01 = B[0][1], a02 = B[0][2];
    float a10 = B[1][0], a11 = B[1][1], a12 = B[1][2];
    float a20 = B[2][0], a21 = B[2][1], a22 = B[2][2];

    float adj00 =  (a11 * a22 - a12 * a21);
    float adj01 = -(a01 * a22 - a02 * a21);
    float adj02 =  (a01 * a12 - a02 * a11);
    float adj10 = -(a10 * a22 - a12 * a20);
    float adj11 =  (a00 * a22 - a02 * a20);
    float adj12 = -(a00 * a12 - a02 * a10);
    float adj20 =  (a10 * a21 - a11 * a20);
    float adj21 = -(a00 * a21 - a01 * a20);
    float adj22 =  (a00 * a11 - a01 * a10);

    float det = a00 * adj00 + a01 * adj10 + a02 * adj20;

    // per-entry division: for diagonal box this rounds identically to
    // LAPACK's 1/pivot (single rounding of the exact quotient).
    Binv[0][0] = __fdiv_rn(adj00, det); Binv[0][1] = __fdiv_rn(adj01, det); Binv[0][2] = __fdiv_rn(adj02, det);
    Binv[1][0] = __fdiv_rn(adj10, det); Binv[1][1] = __fdiv_rn(adj11, det); Binv[1][2] = __fdiv_rn(adj12, det);
    Binv[2][0] = __fdiv_rn(adj20, det); Binv[2][1] = __fdiv_rn(adj21, det); Binv[2][2] = __fdiv_rn(adj22, det);
}

__device__ __forceinline__ bool box_is_diag(const float B[3][3]) {
    return (B[0][1] == 0.0f) & (B[0][2] == 0.0f) & (B[1][0] == 0.0f) &
           (B[1][2] == 0.0f) & (B[2][0] == 0.0f) & (B[2][1] == 0.0f) &
           (B[0][0] > 0.0f) & (B[1][1] > 0.0f) & (B[2][2] > 0.0f);
}

// Cell-grid parameters from a diagonal box. Returns false if unusable.
__device__ __forceinline__ bool cell_params(const float B[3][3],
                                            int& ncx, int& ncy, int& ncz,
                                            float& ivx, float& ivy, float& ivz) {
    float margin = CUTOFF * 1.001f;    // absorb fp32 cell-assignment rounding
    ncx = (int)(B[0][0] / margin);
    ncy = (int)(B[1][1] / margin);
    ncz = (int)(B[2][2] / margin);
    if (ncx < 3 || ncy < 3 || ncz < 3) return false;
    if (ncx > 8) ncx = 8;              // keep nc3 <= MAXC
    if (ncy > 8) ncy = 8;
    if (ncz > 8) ncz = 8;
    ivx = (float)ncx / B[0][0];
    ivy = (float)ncy / B[1][1];
    ivz = (float)ncz / B[2][2];
    return true;
}

// Cell index of a coordinate (must be IDENTICAL in Kbuild and K1).
__device__ __forceinline__ int cell_of_dim(float u, float L, float inv, int nc) {
    u = u - L * floorf(u / L);         // wrap to [0, L)
    int c = (int)(u * inv);
    if (c < 0) c = 0;
    if (c >= nc) c = nc - 1;
    return c;
}

// General triclinic path. Replicates numpy rounding exactly (no FMA):
// delta = pos_i - pos_j; frac = delta @ Binv; delta -= rint(frac) @ B; d2.
__device__ __forceinline__ void min_image(float xi, float yi, float zi,
                                          float xj, float yj, float zj,
                                          const float B[3][3], const float Binv[3][3],
                                          float& dx, float& dy, float& dz, float& d2) {
    dx = __fsub_rn(xi, xj);
    dy = __fsub_rn(yi, yj);
    dz = __fsub_rn(zi, zj);

    float f0 = __fadd_rn(__fadd_rn(__fmul_rn(dx, Binv[0][0]), __fmul_rn(dy, Binv[1][0])), __fmul_rn(dz, Binv[2][0]));
    float f1 = __fadd_rn(__fadd_rn(__fmul_rn(dx, Binv[0][1]), __fmul_rn(dy, Binv[1][1])), __fmul_rn(dz, Binv[2][1]));
    float f2 = __fadd_rn(__fadd_rn(__fmul_rn(dx, Binv[0][2]), __fmul_rn(dy, Binv[1][2])), __fmul_rn(dz, Binv[2][2]));

    float r0 = rintf(f0), r1 = rintf(f1), r2 = rintf(f2);

    float c0 = __fadd_rn(__fadd_rn(__fmul_rn(r0, B[0][0]), __fmul_rn(r1, B[1][0])), __fmul_rn(r2, B[2][0]));
    float c1 = __fadd_rn(__fadd_rn(__fmul_rn(r0, B[0][1]), __fmul_rn(r1, B[1][1])), __fmul_rn(r2, B[2][1]));
    float c2 = __fadd_rn(__fadd_rn(__fmul_rn(r0, B[0][2]), __fmul_rn(r1, B[1][2])), __fmul_rn(r2, B[2][2]));

    dx = __fsub_rn(dx, c0);
    dy = __fsub_rn(dy, c1);
    dz = __fsub_rn(dz, c2);

    d2 = __fadd_rn(__fadd_rn(__fmul_rn(dx, dx), __fmul_rn(dy, dy)), __fmul_rn(dz, dz));
}

// Diagonal-box fast path: same values as the general path when all
// off-diagonal box entries are zero (cross terms are +-0; dropping them can
// only flip sign of an exact zero, which d2 and the wrap subtraction erase).
__device__ __forceinline__ void min_image_diag(float xi, float yi, float zi,
                                               float xj, float yj, float zj,
                                               float b0, float b1, float b2,
                                               float ib0, float ib1, float ib2,
                                               float& dx, float& dy, float& dz, float& d2) {
    dx = __fsub_rn(xi, xj);
    dy = __fsub_rn(yi, yj);
    dz = __fsub_rn(zi, zj);
    float r0 = rintf(__fmul_rn(dx, ib0));
    float r1 = rintf(__fmul_rn(dy, ib1));
    float r2 = rintf(__fmul_rn(dz, ib2));
    dx = __fsub_rn(dx, __fmul_rn(r0, b0));
    dy = __fsub_rn(dy, __fmul_rn(r1, b1));
    dz = __fsub_rn(dz, __fmul_rn(r2, b2));
    d2 = __fadd_rn(__fadd_rn(__fmul_rn(dx, dx), __fmul_rn(dy, dy)), __fmul_rn(dz, dz));
}

// K0a: pad output + zero masks + AoS -> SoA transpose.
__global__ void __launch_bounds__(256)
k0_prep(const float* __restrict__ pos,
        float* __restrict__ X, float* __restrict__ Y, float* __restrict__ Z,
        unsigned long long* __restrict__ masks,
        float* __restrict__ out, int N, int P) {
    int tid = blockIdx.x * blockDim.x + threadIdx.x;
    int nthreads = gridDim.x * blockDim.x;

    int total = 6 * P + 1;
    for (int k = tid; k < total; k += nthreads)
        out[k] = (k < 2 * P) ? -1.0f : 0.0f;

    int nwords = N * (N >> 6) / 64;    // N rows x nchunks words... actually N*nchunks
    nwords = N * (N >> 6);
    for (int k = tid; k < nwords; k += nthreads)
        masks[k] = 0ull;

    if (tid < N) {
        X[tid] = pos[3 * tid + 0];
        Y[tid] = pos[3 * tid + 1];
        Z[tid] = pos[3 * tid + 2];
    }
}

// Kbuild: single-block counting sort of atoms into cells. Writes cellstart
// [nc3+1] and cell-sorted copies jid/Xs/Ys/Zs. No-op when cells unusable.
__global__ void __launch_bounds__(1024)
kbuild(const float* __restrict__ box,
       const float* __restrict__ X, const float* __restrict__ Y,
       const float* __restrict__ Z,
       int* __restrict__ cellstart, int* __restrict__ jid,
       float* __restrict__ Xs, float* __restrict__ Ys, float* __restrict__ Zs,
       int N) {
    __shared__ int hist[MAXC];
    __shared__ int cur[MAXC];

    float B[3][3], Binv[3][3];
    load_box_inv(box, B, Binv);
    int ncx, ncy, ncz; float ivx, ivy, ivz;
    if (!box_is_diag(B) || !cell_params(B, ncx, ncy, ncz, ivx, ivy, ivz))
        return;
    int nc3 = ncx * ncy * ncz;

    int tid = threadIdx.x;
    for (int c = tid; c < nc3; c += 1024) hist[c] = 0;
    __syncthreads();

    for (int a = tid; a < N; a += 1024) {
        int cx = cell_of_dim(X[a], B[0][0], ivx, ncx);
        int cy = cell_of_dim(Y[a], B[1][1], ivy, ncy);
        int cz = cell_of_dim(Z[a], B[2][2], ivz, ncz);
        atomicAdd(&hist[(cz * ncy + cy) * ncx + cx], 1);
    }
    __syncthreads();

    if (tid == 0) {
        int run = 0;
        for (int c = 0; c < nc3; ++c) {
            cellstart[c] = run;
            cur[c] = run;
            run += hist[c];
        }
        cellstart[nc3] = run;
    }
    __syncthreads();

    for (int a = tid; a < N; a += 1024) {
        int cx = cell_of_dim(X[a], B[0][0], ivx, ncx);
        int cy = cell_of_dim(Y[a], B[1][1], ivy, ncy);
        int cz = cell_of_dim(Z[a], B[2][2], ivz, ncz);
        int s = atomicAdd(&cur[(cz * ncy + cy) * ncx + cx], 1);
        jid[s] = a;
        Xs[s] = X[a];
        Ys[s] = Y[a];
        Zs[s] = Z[a];
    }
}

// O(N^2) fallback count (R9's proven path): writes per-chunk masks directly.
template <bool DIAG>
__device__ __forceinline__ int count_row_full(int i, int lane,
                                              const float* __restrict__ X,
                                              const float* __restrict__ Y,
                                              const float* __restrict__ Z,
                                              const float B[3][3], const float Binv[3][3],
                                              unsigned long long* __restrict__ mrow,
                                              int nchunks) {
    float xi = X[i], yi = Y[i], zi = Z[i];
    float b0 = B[0][0], b1 = B[1][1], b2 = B[2][2];
    float ib0 = Binv[0][0], ib1 = Binv[1][1], ib2 = Binv[2][2];
    int c0 = i >> 6;
    int cnt = 0;
    {
        int j = (c0 << 6) + lane;
        bool hit = false;
        if (j > i) {
            float dx, dy, dz, d2;
            if (DIAG)
                min_image_diag(xi, yi, zi, X[j], Y[j], Z[j],
                               b0, b1, b2, ib0, ib1, ib2, dx, dy, dz, d2);
            else
                min_image(xi, yi, zi, X[j], Y[j], Z[j], B, Binv, dx, dy, dz, d2);
            hit = (d2 < CUT2);
        }
        unsigned long long m = __ballot(hit);
        if (lane == 0) mrow[c0] = m;
        cnt += __popcll(m);
    }
    for (int c = c0 + 1; c < nchunks; ++c) {
        int j = (c << 6) + lane;
        float dx, dy, dz, d2;
        if (DIAG)
            min_image_diag(xi, yi, zi, X[j], Y[j], Z[j],
                           b0, b1, b2, ib0, ib1, ib2, dx, dy, dz, d2);
        else
            min_image(xi, yi, zi, X[j], Y[j], Z[j], B, Binv, dx, dy, dz, d2);
        unsigned long long m = __ballot(d2 < CUT2);
        if (lane == 0) mrow[c] = m;
        cnt += __popcll(m);
    }
    return cnt;
}

// K1: one wave per row. Cell path: test atoms of the 27 neighbor cells;
// set hit bits with idempotent atomicOr (order-free); count via ballot.
__global__ void __launch_bounds__(256)
k1_count(const float* __restrict__ X, const float* __restrict__ Y,
         const float* __restrict__ Z, const float* __restrict__ box,
         const int* __restrict__ cellstart, const int* __restrict__ jid,
         const float* __restrict__ Xs, const float* __restrict__ Ys,
         const float* __restrict__ Zs,
         int* __restrict__ counts, unsigned long long* __restrict__ masks,
         int N, int P) {
    int tid = blockIdx.x * blockDim.x + threadIdx.x;
    int i = tid >> 6;
    int lane = tid & 63;
    int nchunks = N >> 6;

    float B[3][3], Binv[3][3];
    load_box_inv(box, B, Binv);
    bool diag = box_is_diag(B);
    int ncx, ncy, ncz; float ivx, ivy, ivz;
    bool cells = diag && cell_params(B, ncx, ncy, ncz, ivx, ivy, ivz);

    unsigned long long* mrow = masks + (size_t)i * nchunks;

    if (cells) {
        float xi = X[i], yi = Y[i], zi = Z[i];
        float b0 = B[0][0], b1 = B[1][1], b2 = B[2][2];
        float ib0 = Binv[0][0], ib1 = Binv[1][1], ib2 = Binv[2][2];
        int icx = cell_of_dim(xi, b0, ivx, ncx);
        int icy = cell_of_dim(yi, b1, ivy, ncy);
        int icz = cell_of_dim(zi, b2, ivz, ncz);

        int cnt = 0;
        #pragma unroll
        for (int dz = -1; dz <= 1; ++dz) {
            int cz = icz + dz; cz += (cz < 0) ? ncz : 0; cz -= (cz >= ncz) ? ncz : 0;
            #pragma unroll
            for (int dy = -1; dy <= 1; ++dy) {
                int cy = icy + dy; cy += (cy < 0) ? ncy : 0; cy -= (cy >= ncy) ? ncy : 0;
                #pragma unroll
                for (int dx = -1; dx <= 1; ++dx) {
                    int cx = icx + dx; cx += (cx < 0) ? ncx : 0; cx -= (cx >= ncx) ? ncx : 0;
                    int c = (cz * ncy + cy) * ncx + cx;
                    int s = cellstart[c], e = cellstart[c + 1];
                    for (int off = s; off < e; off += 64) {
                        int k = off + lane;
                        bool hit = false;
                        int j = 0;
                        if (k < e) {
                            j = jid[k];
                            float ddx, ddy, ddz, d2;
                            min_image_diag(xi, yi, zi, Xs[k], Ys[k], Zs[k],
                                           b0, b1, b2, ib0, ib1, ib2,
                                           ddx, ddy, ddz, d2);
                            hit = (d2 < CUT2) & (j > i);
                        }
                        unsigned long long m = __ballot(hit);
                        cnt += __popcll(m);
                        if (hit)
                            atomicOr(&mrow[j >> 6], 1ull << (j & 63));
                    }
                }
            }
        }
        if (lane == 0) counts[i] = cnt;
    } else {
        int cnt;
        if (diag)
            cnt = count_row_full<true>(i, lane, X, Y, Z, B, Binv, mrow, nchunks);
        else
            cnt = count_row_full<false>(i, lane, X, Y, Z, B, Binv, mrow, nchunks);
        if (lane == 0) counts[i] = cnt;
    }
}

// K2: one wave per row. int4 prefix over counts[0..i), then ordered fill of
// hits from the masks (general math path, value-identical to numpy).
__global__ void __launch_bounds__(256)
k2_scan_fill(const float* __restrict__ X, const float* __restrict__ Y,
             const float* __restrict__ Z, const float* __restrict__ box,
             const int* __restrict__ counts,
             const unsigned long long* __restrict__ masks,
             float* __restrict__ out, int N, int P) {
    int tid = blockIdx.x * blockDim.x + threadIdx.x;
    int i = tid >> 6;
    int lane = tid & 63;
    int nchunks = N >> 6;
    int c0 = i >> 6;

    int pre = 0;
    for (int base = 0; base < i; base += 256) {
        int idx = base + 4 * lane;
        int4 v = *(const int4*)(counts + idx);   // may read past i; masked below
        if (idx + 0 < i) pre += v.x;
        if (idx + 1 < i) pre += v.y;
        if (idx + 2 < i) pre += v.z;
        if (idx + 3 < i) pre += v.w;
    }
    #pragma unroll
    for (int d = 1; d < 64; d <<= 1)
        pre += __shfl_xor(pre, d);               // all lanes: sum counts[0..i)

    if (i == N - 1 && lane == 0)
        out[6 * (size_t)P] = (float)(pre + counts[i]);   // n_pairs

    unsigned long long mymask = masks[(size_t)i * nchunks + lane];

    float B[3][3], Binv[3][3];
    load_box_inv(box, B, Binv);
    float xi = X[i], yi = Y[i], zi = Z[i];

    int base = pre;
    for (int cc = c0; cc < nchunks; ++cc) {
        unsigned long long m = __shfl(mymask, cc);
        if (m != 0ull) {
            if ((m >> lane) & 1ull) {
                int j = (cc << 6) + lane;
                float dx, dy, dz, d2;
                min_image(xi, yi, zi, X[j], Y[j], Z[j], B, Binv, dx, dy, dz, d2);
                int slot = base + __popcll(m & ((1ull << lane) - 1ull));
                if (slot < P) {
                    out[slot] = (float)i;                    // pair_i
                    out[P + slot] = (float)j;                // pair_j
                    size_t db = 2 * (size_t)P + 3 * (size_t)slot;
                    out[db + 0] = dx;
                    out[db + 1] = dy;
                    out[db + 2] = dz;
                    out[5 * (size_t)P + slot] = sqrtf(d2);   // distance
                }
            }
            base += __popcll(m);
        }
    }
}

extern "C" void kernel_launch(void* const* d_in, const int* in_sizes, int n_in,
                              void* d_out, int out_size, void* d_ws, size_t ws_size,
                              hipStream_t stream) {
    const float* pos = (const float*)d_in[0];
    const float* box = (const float*)d_in[1];
    float* out = (float*)d_out;

    int N = in_sizes[0] / 3;          // 4096
    int P = (out_size - 1) / 6;       // 131072
    int nchunks = N >> 6;

    // ws: X[N] Y[N] Z[N] counts[N] | masks[N*nchunks] | cellstart[MAXC+1] |
    //     jid[N] Xs[N] Ys[N] Zs[N]
    char* w = (char*)d_ws;
    float* X = (float*)w;                          w += (size_t)N * sizeof(float);
    float* Y = (float*)w;                          w += (size_t)N * sizeof(float);
    float* Z = (float*)w;                          w += (size_t)N * sizeof(float);
    int* counts = (int*)w;                         w += (size_t)N * sizeof(int);
    unsigned long long* masks = (unsigned long long*)w;
                                                   w += (size_t)N * nchunks * sizeof(unsigned long long);
    int* cellstart = (int*)w;                      w += (size_t)(MAXC + 1) * sizeof(int);
    int* jid = (int*)w;                            w += (size_t)N * sizeof(int);
    float* Xs = (float*)w;                         w += (size_t)N * sizeof(float);
    float* Ys = (float*)w;                         w += (size_t)N * sizeof(float);
    float* Zs = (float*)w;

    k0_prep<<<1024, 256, 0, stream>>>(pos, X, Y, Z, masks, out, N, P);
    kbuild<<<1, 1024, 0, stream>>>(box, X, Y, Z, cellstart, jid, Xs, Ys, Zs, N);
    k1_count<<<N / 4, 256, 0, stream>>>(X, Y, Z, box, cellstart, jid, Xs, Ys, Zs,
                                        counts, masks, N, P);
    k2_scan_fill<<<N / 4, 256, 0, stream>>>(X, Y, Z, box, counts, masks, out, N, P);
}

// Round 11
// 89.554 us; speedup vs baseline: 1.2918x; 1.2918x over previous
//
#include <hip/hip_runtime.h>

// NeighborList: N atoms, minimum-image convention, cutoff 5.0.
// Output layout (all float32): pairs[2*P], deltas[P*3], distances[P], n_pairs[1]
// Ordering must match jnp.nonzero(mask.ravel()) -> ascending flat index i*N+j.
//
// TWO dispatches -- minimal structure. Hard-won notes (R1-R10):
//  - NO intra-kernel global sync: cg grid.sync = 140us (R3), spin = 535us (R8).
//  - Cell list regressed (R10: +29us): lane utilization collapse beats the
//    6.4x candidate cut. Occupancy/balance/LDS/SoA levers all neutral.
//  - Only instruction-count cuts move dur. This round: no mask workspace at
//    all. K1 counts only; K2 recomputes each chunk's ballot (same diag math
//    -> identical mask) and fills immediately. Saves mask stores+loads+shfl
//    and one dispatch (no SoA transpose; AoS proven equal).
//  - Diagonal-box fast path for the hit test (values identical: dropped
//    cross terms are +-0); written values use the general path.

#define CUT2 25.0f

__device__ __forceinline__ void load_box_inv(const float* __restrict__ box,
                                             float B[3][3], float Binv[3][3]) {
    #pragma unroll
    for (int r = 0; r < 3; ++r)
        #pragma unroll
        for (int c = 0; c < 3; ++c)
            B[r][c] = box[r * 3 + c];

    float a00 = B[0][0], a01 = B[0][1], a02 = B[0][2];
    float a10 = B[1][0], a11 = B[1][1], a12 = B[1][2];
    float a20 = B[2][0], a21 = B[2][1], a22 = B[2][2];

    float adj00 =  (a11 * a22 - a12 * a21);
    float adj01 = -(a01 * a22 - a02 * a21);
    float adj02 =  (a01 * a12 - a02 * a11);
    float adj10 = -(a10 * a22 - a12 * a20);
    float adj11 =  (a00 * a22 - a02 * a20);
    float adj12 = -(a00 * a12 - a02 * a10);
    float adj20 =  (a10 * a21 - a11 * a20);
    float adj21 = -(a00 * a21 - a01 * a20);
    float adj22 =  (a00 * a11 - a01 * a10);

    float det = a00 * adj00 + a01 * adj10 + a02 * adj20;

    // per-entry division: for diagonal box this rounds identically to
    // LAPACK's 1/pivot (single rounding of the exact quotient).
    Binv[0][0] = __fdiv_rn(adj00, det); Binv[0][1] = __fdiv_rn(adj01, det); Binv[0][2] = __fdiv_rn(adj02, det);
    Binv[1][0] = __fdiv_rn(adj10, det); Binv[1][1] = __fdiv_rn(adj11, det); Binv[1][2] = __fdiv_rn(adj12, det);
    Binv[2][0] = __fdiv_rn(adj20, det); Binv[2][1] = __fdiv_rn(adj21, det); Binv[2][2] = __fdiv_rn(adj22, det);
}

// General triclinic path. Replicates numpy rounding exactly (no FMA):
// delta = pos_i - pos_j; frac = delta @ Binv; delta -= rint(frac) @ B; d2.
__device__ __forceinline__ void min_image(float xi, float yi, float zi,
                                          float xj, float yj, float zj,
                                          const float B[3][3], const float Binv[3][3],
                                          float& dx, float& dy, float& dz, float& d2) {
    dx = __fsub_rn(xi, xj);
    dy = __fsub_rn(yi, yj);
    dz = __fsub_rn(zi, zj);

    float f0 = __fadd_rn(__fadd_rn(__fmul_rn(dx, Binv[0][0]), __fmul_rn(dy, Binv[1][0])), __fmul_rn(dz, Binv[2][0]));
    float f1 = __fadd_rn(__fadd_rn(__fmul_rn(dx, Binv[0][1]), __fmul_rn(dy, Binv[1][1])), __fmul_rn(dz, Binv[2][1]));
    float f2 = __fadd_rn(__fadd_rn(__fmul_rn(dx, Binv[0][2]), __fmul_rn(dy, Binv[1][2])), __fmul_rn(dz, Binv[2][2]));

    float r0 = rintf(f0), r1 = rintf(f1), r2 = rintf(f2);

    float c0 = __fadd_rn(__fadd_rn(__fmul_rn(r0, B[0][0]), __fmul_rn(r1, B[1][0])), __fmul_rn(r2, B[2][0]));
    float c1 = __fadd_rn(__fadd_rn(__fmul_rn(r0, B[0][1]), __fmul_rn(r1, B[1][1])), __fmul_rn(r2, B[2][1]));
    float c2 = __fadd_rn(__fadd_rn(__fmul_rn(r0, B[0][2]), __fmul_rn(r1, B[1][2])), __fmul_rn(r2, B[2][2]));

    dx = __fsub_rn(dx, c0);
    dy = __fsub_rn(dy, c1);
    dz = __fsub_rn(dz, c2);

    d2 = __fadd_rn(__fadd_rn(__fmul_rn(dx, dx), __fmul_rn(dy, dy)), __fmul_rn(dz, dz));
}

// Diagonal-box fast path: same values as the general path when all
// off-diagonal box entries are zero (cross terms are +-0; dropping them can
// only flip sign of an exact zero, which d2 and the wrap subtraction erase).
__device__ __forceinline__ void min_image_diag(float xi, float yi, float zi,
                                               float xj, float yj, float zj,
                                               float b0, float b1, float b2,
                                               float ib0, float ib1, float ib2,
                                               float& dx, float& dy, float& dz, float& d2) {
    dx = __fsub_rn(xi, xj);
    dy = __fsub_rn(yi, yj);
    dz = __fsub_rn(zi, zj);
    float r0 = rintf(__fmul_rn(dx, ib0));
    float r1 = rintf(__fmul_rn(dy, ib1));
    float r2 = rintf(__fmul_rn(dz, ib2));
    dx = __fsub_rn(dx, __fmul_rn(r0, b0));
    dy = __fsub_rn(dy, __fmul_rn(r1, b1));
    dz = __fsub_rn(dz, __fmul_rn(r2, b2));
    d2 = __fadd_rn(__fadd_rn(__fmul_rn(dx, dx), __fmul_rn(dy, dy)), __fmul_rn(dz, dz));
}

// Per-chunk hit mask for row i, chunk c (all lanes; ballot).
template <bool DIAG>
__device__ __forceinline__ unsigned long long
chunk_mask(int i, int lane, int c, int c0,
           float xi, float yi, float zi,
           const float* __restrict__ pos,
           const float B[3][3], const float Binv[3][3]) {
    int j = (c << 6) + lane;
    float b0 = B[0][0], b1 = B[1][1], b2 = B[2][2];
    float ib0 = Binv[0][0], ib1 = Binv[1][1], ib2 = Binv[2][2];
    bool hit;
    float dx, dy, dz, d2;
    if (DIAG)
        min_image_diag(xi, yi, zi, pos[3 * j], pos[3 * j + 1], pos[3 * j + 2],
                       b0, b1, b2, ib0, ib1, ib2, dx, dy, dz, d2);
    else
        min_image(xi, yi, zi, pos[3 * j], pos[3 * j + 1], pos[3 * j + 2],
                  B, Binv, dx, dy, dz, d2);
    hit = (d2 < CUT2);
    if (c == c0) hit &= (j > i);       // diagonal chunk predicate
    return __ballot(hit);
}

// K1: pad output + count-only (no mask stores). One wave per row.
template <bool DIAG>
__device__ __forceinline__ int count_row(int i, int lane,
                                         const float* __restrict__ pos,
                                         const float B[3][3], const float Binv[3][3],
                                         int nchunks) {
    float xi = pos[3 * i + 0], yi = pos[3 * i + 1], zi = pos[3 * i + 2];
    int c0 = i >> 6;
    int cnt = __popcll(chunk_mask<DIAG>(i, lane, c0, c0, xi, yi, zi, pos, B, Binv));

    int c = c0 + 1;
    for (; c + 4 <= nchunks; c += 4) {
        unsigned long long m0 = chunk_mask<DIAG>(i, lane, c + 0, c0, xi, yi, zi, pos, B, Binv);
        unsigned long long m1 = chunk_mask<DIAG>(i, lane, c + 1, c0, xi, yi, zi, pos, B, Binv);
        unsigned long long m2 = chunk_mask<DIAG>(i, lane, c + 2, c0, xi, yi, zi, pos, B, Binv);
        unsigned long long m3 = chunk_mask<DIAG>(i, lane, c + 3, c0, xi, yi, zi, pos, B, Binv);
        cnt += __popcll(m0) + __popcll(m1) + __popcll(m2) + __popcll(m3);
    }
    for (; c < nchunks; ++c)
        cnt += __popcll(chunk_mask<DIAG>(i, lane, c, c0, xi, yi, zi, pos, B, Binv));
    return cnt;
}

__global__ void __launch_bounds__(256)
k1_pad_count(const float* __restrict__ pos, const float* __restrict__ box,
             float* __restrict__ out, int* __restrict__ counts, int N, int P) {
    int tid = blockIdx.x * blockDim.x + threadIdx.x;
    int nthreads = gridDim.x * blockDim.x;   // N*64

    // pad: pairs = -1, rest = 0 (stores retire while we compute)
    int total = 6 * P + 1;
    for (int k = tid; k < total; k += nthreads)
        out[k] = (k < 2 * P) ? -1.0f : 0.0f;

    int i = tid >> 6;
    int lane = tid & 63;
    int nchunks = N >> 6;

    float B[3][3], Binv[3][3];
    load_box_inv(box, B, Binv);
    bool diag = (B[0][1] == 0.0f) & (B[0][2] == 0.0f) & (B[1][0] == 0.0f) &
                (B[1][2] == 0.0f) & (B[2][0] == 0.0f) & (B[2][1] == 0.0f);

    int cnt = diag ? count_row<true>(i, lane, pos, B, Binv, nchunks)
                   : count_row<false>(i, lane, pos, B, Binv, nchunks);
    if (lane == 0) counts[i] = cnt;
}

// K2: one wave per row. int4 prefix over counts[0..i); then re-walk the row
// recomputing each chunk's ballot (identical mask) and writing hits in order.
__global__ void __launch_bounds__(256)
k2_scan_fill(const float* __restrict__ pos, const float* __restrict__ box,
             const int* __restrict__ counts,
             float* __restrict__ out, int N, int P) {
    int tid = blockIdx.x * blockDim.x + threadIdx.x;
    int i = tid >> 6;
    int lane = tid & 63;
    int nchunks = N >> 6;
    int c0 = i >> 6;

    // Exclusive prefix over counts[0..i) via int4 loads + butterfly.
    int pre = 0;
    for (int base = 0; base < i; base += 256) {
        int idx = base + 4 * lane;
        int4 v = *(const int4*)(counts + idx);   // padded past N; masked below
        if (idx + 0 < i) pre += v.x;
        if (idx + 1 < i) pre += v.y;
        if (idx + 2 < i) pre += v.z;
        if (idx + 3 < i) pre += v.w;
    }
    #pragma unroll
    for (int d = 1; d < 64; d <<= 1)
        pre += __shfl_xor(pre, d);               // all lanes: sum counts[0..i)

    if (i == N - 1 && lane == 0)
        out[6 * (size_t)P] = (float)(pre + counts[i]);   // n_pairs

    float B[3][3], Binv[3][3];
    load_box_inv(box, B, Binv);
    bool diag = (B[0][1] == 0.0f) & (B[0][2] == 0.0f) & (B[1][0] == 0.0f) &
                (B[1][2] == 0.0f) & (B[2][0] == 0.0f) & (B[2][1] == 0.0f);
    float xi = pos[3 * i + 0], yi = pos[3 * i + 1], zi = pos[3 * i + 2];

    int base = pre;
    for (int cc = c0; cc < nchunks; ++cc) {
        unsigned long long m =
            diag ? chunk_mask<true>(i, lane, cc, c0, xi, yi, zi, pos, B, Binv)
                 : chunk_mask<false>(i, lane, cc, c0, xi, yi, zi, pos, B, Binv);
        if (m != 0ull) {
            if ((m >> lane) & 1ull) {
                int j = (cc << 6) + lane;
                float dx, dy, dz, d2;
                // written values: validated general path (hits only, ~69K)
                min_image(xi, yi, zi, pos[3 * j + 0], pos[3 * j + 1], pos[3 * j + 2],
                          B, Binv, dx, dy, dz, d2);
                int slot = base + __popcll(m & ((1ull << lane) - 1ull));
                if (slot < P) {
                    out[slot] = (float)i;                    // pair_i
                    out[P + slot] = (float)j;                // pair_j
                    size_t db = 2 * (size_t)P + 3 * (size_t)slot;
                    out[db + 0] = dx;
                    out[db + 1] = dy;
                    out[db + 2] = dz;
                    out[5 * (size_t)P + slot] = sqrtf(d2);   // distance
                }
            }
            base += __popcll(m);
        }
    }
}

extern "C" void kernel_launch(void* const* d_in, const int* in_sizes, int n_in,
                              void* d_out, int out_size, void* d_ws, size_t ws_size,
                              hipStream_t stream) {
    const float* pos = (const float*)d_in[0];
    const float* box = (const float*)d_in[1];
    float* out = (float*)d_out;

    int N = in_sizes[0] / 3;          // 4096
    int P = (out_size - 1) / 6;       // 131072

    int* counts = (int*)d_ws;         // N + 256 ints (padded for int4 sweep)

    // One wave per row: N/4 blocks of 256.
    k1_pad_count<<<N / 4, 256, 0, stream>>>(pos, box, out, counts, N, P);
    k2_scan_fill<<<N / 4, 256, 0, stream>>>(pos, box, counts, out, N, P);
}

// Round 12
// 87.036 us; speedup vs baseline: 1.3292x; 1.0289x over previous
//
#include <hip/hip_runtime.h>

// NeighborList: N atoms, minimum-image convention, cutoff 5.0.
// Output layout (all float32): pairs[2*P], deltas[P*3], distances[P], n_pairs[1]
// Ordering must match jnp.nonzero(mask.ravel()) -> ascending flat index i*N+j.
//
// BEST MEASURED VARIANT (R9, 87.0us) -- reverted after R10 (cell list, +29us)
// and R11 (mask-free recompute, +2.5us) both regressed. Hard-won notes:
//  - NO intra-kernel global sync: cg grid.sync = 140us (R3), hand-rolled
//    acquire/release spin = 535us (R8) on this 8-XCD chip.
//  - Cell-list pruning loses to brute force at N=4096/cutoff5/box40: lane
//    utilization collapse (12-atom cells on 64-lane waves) + atomics.
//  - Storing per-chunk masks beats recomputing them in K2 (R11).
//  - Occupancy x2, heavy/light balance, LDS staging, AoS->SoA: all neutral;
//    only instruction-count cuts (diag fast path) ever moved dur.
//  - K0: AoS->SoA. K1: pad + per-row count + per-chunk 64-bit hit masks
//    (1 wave/row). K2: per-wave int4 prefix over counts + ordered fill.
//  - Diagonal-box fast path (values identical: dropped cross terms are +-0);
//    written values use the validated general path (hits only).

#define CUT2 25.0f

__device__ __forceinline__ void load_box_inv(const float* __restrict__ box,
                                             float B[3][3], float Binv[3][3]) {
    #pragma unroll
    for (int r = 0; r < 3; ++r)
        #pragma unroll
        for (int c = 0; c < 3; ++c)
            B[r][c] = box[r * 3 + c];

    float a00 = B[0][0], a01 = B[0][1], a02 = B[0][2];
    float a10 = B[1][0], a11 = B[1][1], a12 = B[1][2];
    float a20 = B[2][0], a21 = B[2][1], a22 = B[2][2];

    float adj00 =  (a11 * a22 - a12 * a21);
    float adj01 = -(a01 * a22 - a02 * a21);
    float adj02 =  (a01 * a12 - a02 * a11);
    float adj10 = -(a10 * a22 - a12 * a20);
    float adj11 =  (a00 * a22 - a02 * a20);
    float adj12 = -(a00 * a12 - a02 * a10);
    float adj20 =  (a10 * a21 - a11 * a20);
    float adj21 = -(a00 * a21 - a01 * a20);
    float adj22 =  (a00 * a11 - a01 * a10);

    float det = a00 * adj00 + a01 * adj10 + a02 * adj20;

    // per-entry division: for diagonal box this rounds identically to
    // LAPACK's 1/pivot (single rounding of the exact quotient).
    Binv[0][0] = __fdiv_rn(adj00, det); Binv[0][1] = __fdiv_rn(adj01, det); Binv[0][2] = __fdiv_rn(adj02, det);
    Binv[1][0] = __fdiv_rn(adj10, det); Binv[1][1] = __fdiv_rn(adj11, det); Binv[1][2] = __fdiv_rn(adj12, det);
    Binv[2][0] = __fdiv_rn(adj20, det); Binv[2][1] = __fdiv_rn(adj21, det); Binv[2][2] = __fdiv_rn(adj22, det);
}

// General triclinic path. Replicates numpy rounding exactly (no FMA):
// delta = pos_i - pos_j; frac = delta @ Binv; delta -= rint(frac) @ B; d2.
__device__ __forceinline__ void min_image(float xi, float yi, float zi,
                                          float xj, float yj, float zj,
                                          const float B[3][3], const float Binv[3][3],
                                          float& dx, float& dy, float& dz, float& d2) {
    dx = __fsub_rn(xi, xj);
    dy = __fsub_rn(yi, yj);
    dz = __fsub_rn(zi, zj);

    float f0 = __fadd_rn(__fadd_rn(__fmul_rn(dx, Binv[0][0]), __fmul_rn(dy, Binv[1][0])), __fmul_rn(dz, Binv[2][0]));
    float f1 = __fadd_rn(__fadd_rn(__fmul_rn(dx, Binv[0][1]), __fmul_rn(dy, Binv[1][1])), __fmul_rn(dz, Binv[2][1]));
    float f2 = __fadd_rn(__fadd_rn(__fmul_rn(dx, Binv[0][2]), __fmul_rn(dy, Binv[1][2])), __fmul_rn(dz, Binv[2][2]));

    float r0 = rintf(f0), r1 = rintf(f1), r2 = rintf(f2);

    float c0 = __fadd_rn(__fadd_rn(__fmul_rn(r0, B[0][0]), __fmul_rn(r1, B[1][0])), __fmul_rn(r2, B[2][0]));
    float c1 = __fadd_rn(__fadd_rn(__fmul_rn(r0, B[0][1]), __fmul_rn(r1, B[1][1])), __fmul_rn(r2, B[2][1]));
    float c2 = __fadd_rn(__fadd_rn(__fmul_rn(r0, B[0][2]), __fmul_rn(r1, B[1][2])), __fmul_rn(r2, B[2][2]));

    dx = __fsub_rn(dx, c0);
    dy = __fsub_rn(dy, c1);
    dz = __fsub_rn(dz, c2);

    d2 = __fadd_rn(__fadd_rn(__fmul_rn(dx, dx), __fmul_rn(dy, dy)), __fmul_rn(dz, dz));
}

// Diagonal-box fast path: same values as the general path when all
// off-diagonal box entries are zero (cross terms are +-0; dropping them can
// only flip sign of an exact zero, which d2 and the wrap subtraction erase).
__device__ __forceinline__ void min_image_diag(float xi, float yi, float zi,
                                               float xj, float yj, float zj,
                                               float b0, float b1, float b2,
                                               float ib0, float ib1, float ib2,
                                               float& dx, float& dy, float& dz, float& d2) {
    dx = __fsub_rn(xi, xj);
    dy = __fsub_rn(yi, yj);
    dz = __fsub_rn(zi, zj);
    float r0 = rintf(__fmul_rn(dx, ib0));
    float r1 = rintf(__fmul_rn(dy, ib1));
    float r2 = rintf(__fmul_rn(dz, ib2));
    dx = __fsub_rn(dx, __fmul_rn(r0, b0));
    dy = __fsub_rn(dy, __fmul_rn(r1, b1));
    dz = __fsub_rn(dz, __fmul_rn(r2, b2));
    d2 = __fadd_rn(__fadd_rn(__fmul_rn(dx, dx), __fmul_rn(dy, dy)), __fmul_rn(dz, dz));
}

// K0: transpose positions [N,3] AoS -> SoA X/Y/Z (exact copy, no math).
__global__ void __launch_bounds__(256)
k0_transpose(const float* __restrict__ pos,
             float* __restrict__ X, float* __restrict__ Y, float* __restrict__ Z,
             int N) {
    int idx = blockIdx.x * blockDim.x + threadIdx.x;
    if (idx < N) {
        X[idx] = pos[3 * idx + 0];
        Y[idx] = pos[3 * idx + 1];
        Z[idx] = pos[3 * idx + 2];
    }
}

// Count hits for row i (j > i) from SoA; write per-chunk masks to mrow[].
template <bool DIAG>
__device__ __forceinline__ int count_row(int i, int lane,
                                         const float* __restrict__ X,
                                         const float* __restrict__ Y,
                                         const float* __restrict__ Z,
                                         const float B[3][3], const float Binv[3][3],
                                         unsigned long long* __restrict__ mrow,
                                         int nchunks) {
    float xi = X[i], yi = Y[i], zi = Z[i];
    float b0 = B[0][0], b1 = B[1][1], b2 = B[2][2];
    float ib0 = Binv[0][0], ib1 = Binv[1][1], ib2 = Binv[2][2];
    int c0 = i >> 6;
    int cnt = 0;

    // Diagonal chunk: needs the j>i predicate.
    {
        int j = (c0 << 6) + lane;
        bool hit = false;
        if (j > i) {
            float dx, dy, dz, d2;
            if (DIAG)
                min_image_diag(xi, yi, zi, X[j], Y[j], Z[j],
                               b0, b1, b2, ib0, ib1, ib2, dx, dy, dz, d2);
            else
                min_image(xi, yi, zi, X[j], Y[j], Z[j], B, Binv, dx, dy, dz, d2);
            hit = (d2 < CUT2);
        }
        unsigned long long m = __ballot(hit);
        if (lane == 0) mrow[c0] = m;
        cnt += __popcll(m);
    }

    // Remaining chunks: all j > i. Unroll x4 for ILP.
    int c = c0 + 1;
    for (; c + 4 <= nchunks; c += 4) {
        int j0 = (c << 6) + lane;
        float dx0, dy0, dz0, d20, dx1, dy1, dz1, d21;
        float dx2, dy2, dz2, d22, dx3, dy3, dz3, d23;
        if (DIAG) {
            min_image_diag(xi, yi, zi, X[j0 +   0], Y[j0 +   0], Z[j0 +   0], b0, b1, b2, ib0, ib1, ib2, dx0, dy0, dz0, d20);
            min_image_diag(xi, yi, zi, X[j0 +  64], Y[j0 +  64], Z[j0 +  64], b0, b1, b2, ib0, ib1, ib2, dx1, dy1, dz1, d21);
            min_image_diag(xi, yi, zi, X[j0 + 128], Y[j0 + 128], Z[j0 + 128], b0, b1, b2, ib0, ib1, ib2, dx2, dy2, dz2, d22);
            min_image_diag(xi, yi, zi, X[j0 + 192], Y[j0 + 192], Z[j0 + 192], b0, b1, b2, ib0, ib1, ib2, dx3, dy3, dz3, d23);
        } else {
            min_image(xi, yi, zi, X[j0 +   0], Y[j0 +   0], Z[j0 +   0], B, Binv, dx0, dy0, dz0, d20);
            min_image(xi, yi, zi, X[j0 +  64], Y[j0 +  64], Z[j0 +  64], B, Binv, dx1, dy1, dz1, d21);
            min_image(xi, yi, zi, X[j0 + 128], Y[j0 + 128], Z[j0 + 128], B, Binv, dx2, dy2, dz2, d22);
            min_image(xi, yi, zi, X[j0 + 192], Y[j0 + 192], Z[j0 + 192], B, Binv, dx3, dy3, dz3, d23);
        }
        unsigned long long m0 = __ballot(d20 < CUT2);
        unsigned long long m1 = __ballot(d21 < CUT2);
        unsigned long long m2 = __ballot(d22 < CUT2);
        unsigned long long m3 = __ballot(d23 < CUT2);
        if (lane == 0) { mrow[c] = m0; mrow[c + 1] = m1; mrow[c + 2] = m2; mrow[c + 3] = m3; }
        cnt += __popcll(m0) + __popcll(m1) + __popcll(m2) + __popcll(m3);
    }
    for (; c < nchunks; ++c) {
        int j = (c << 6) + lane;
        float dx, dy, dz, d2;
        if (DIAG)
            min_image_diag(xi, yi, zi, X[j], Y[j], Z[j],
                           b0, b1, b2, ib0, ib1, ib2, dx, dy, dz, d2);
        else
            min_image(xi, yi, zi, X[j], Y[j], Z[j], B, Binv, dx, dy, dz, d2);
        unsigned long long m = __ballot(d2 < CUT2);
        if (lane == 0) mrow[c] = m;
        cnt += __popcll(m);
    }
    return cnt;
}

// K1: pad output + count one row per wave + write masks.
__global__ void __launch_bounds__(256)
k1_pad_count(const float* __restrict__ X, const float* __restrict__ Y,
             const float* __restrict__ Z, const float* __restrict__ box,
             float* __restrict__ out, int* __restrict__ counts,
             unsigned long long* __restrict__ masks, int N, int P) {
    int tid = blockIdx.x * blockDim.x + threadIdx.x;
    int nthreads = gridDim.x * blockDim.x;   // N*64

    // pad: pairs = -1, rest = 0 (stores retire while we compute)
    int total = 6 * P + 1;
    for (int k = tid; k < total; k += nthreads)
        out[k] = (k < 2 * P) ? -1.0f : 0.0f;

    int i = tid >> 6;
    int lane = tid & 63;
    int nchunks = N >> 6;

    float B[3][3], Binv[3][3];
    load_box_inv(box, B, Binv);
    bool diag = (B[0][1] == 0.0f) & (B[0][2] == 0.0f) & (B[1][0] == 0.0f) &
                (B[1][2] == 0.0f) & (B[2][0] == 0.0f) & (B[2][1] == 0.0f);

    int cnt;
    if (diag)
        cnt = count_row<true>(i, lane, X, Y, Z, B, Binv,
                              masks + (size_t)i * nchunks, nchunks);
    else
        cnt = count_row<false>(i, lane, X, Y, Z, B, Binv,
                               masks + (size_t)i * nchunks, nchunks);
    if (lane == 0) counts[i] = cnt;
}

// K2: one wave per row. int4 prefix over counts[0..i), then ordered fill of
// hits from the precomputed masks (general math path, SoA gathers).
__global__ void __launch_bounds__(256)
k2_scan_fill(const float* __restrict__ X, const float* __restrict__ Y,
             const float* __restrict__ Z, const float* __restrict__ box,
             const int* __restrict__ counts,
             const unsigned long long* __restrict__ masks,
             float* __restrict__ out, int N, int P) {
    int tid = blockIdx.x * blockDim.x + threadIdx.x;
    int i = tid >> 6;
    int lane = tid & 63;
    int nchunks = N >> 6;
    int c0 = i >> 6;

    // Exclusive prefix over counts[0..i) via int4 loads + butterfly.
    int pre = 0;
    for (int base = 0; base < i; base += 256) {
        int idx = base + 4 * lane;
        int4 v = *(const int4*)(counts + idx);   // may read past i; masked below
        if (idx + 0 < i) pre += v.x;
        if (idx + 1 < i) pre += v.y;
        if (idx + 2 < i) pre += v.z;
        if (idx + 3 < i) pre += v.w;
    }
    #pragma unroll
    for (int d = 1; d < 64; d <<= 1)
        pre += __shfl_xor(pre, d);               // all lanes: sum counts[0..i)

    if (i == N - 1 && lane == 0)
        out[6 * (size_t)P] = (float)(pre + counts[i]);   // n_pairs

    // lane l holds the mask of chunk l for this row (only cc >= c0 consumed).
    unsigned long long mymask = masks[(size_t)i * nchunks + lane];

    float B[3][3], Binv[3][3];
    load_box_inv(box, B, Binv);
    float xi = X[i], yi = Y[i], zi = Z[i];

    int base = pre;
    for (int cc = c0; cc < nchunks; ++cc) {
        unsigned long long m = __shfl(mymask, cc);
        if (m != 0ull) {
            if ((m >> lane) & 1ull) {
                int j = (cc << 6) + lane;
                float dx, dy, dz, d2;
                min_image(xi, yi, zi, X[j], Y[j], Z[j], B, Binv, dx, dy, dz, d2);
                int slot = base + __popcll(m & ((1ull << lane) - 1ull));
                if (slot < P) {
                    out[slot] = (float)i;                    // pair_i
                    out[P + slot] = (float)j;                // pair_j
                    size_t db = 2 * (size_t)P + 3 * (size_t)slot;
                    out[db + 0] = dx;
                    out[db + 1] = dy;
                    out[db + 2] = dz;
                    out[5 * (size_t)P + slot] = sqrtf(d2);   // distance
                }
            }
            base += __popcll(m);
        }
    }
}

extern "C" void kernel_launch(void* const* d_in, const int* in_sizes, int n_in,
                              void* d_out, int out_size, void* d_ws, size_t ws_size,
                              hipStream_t stream) {
    const float* pos = (const float*)d_in[0];
    const float* box = (const float*)d_in[1];
    float* out = (float*)d_out;

    int N = in_sizes[0] / 3;          // 4096
    int P = (out_size - 1) / 6;       // 131072
    int nchunks = N >> 6;

    // ws layout: X[N] | Y[N] | Z[N] | counts[N] | masks[N*nchunks]
    char* w = (char*)d_ws;
    float* X = (float*)w;                          w += (size_t)N * sizeof(float);
    float* Y = (float*)w;                          w += (size_t)N * sizeof(float);
    float* Z = (float*)w;                          w += (size_t)N * sizeof(float);
    int* counts = (int*)w;                         w += (size_t)N * sizeof(int);
    unsigned long long* masks = (unsigned long long*)w;

    // K0: AoS -> SoA transpose (tiny).
    k0_transpose<<<(N + 255) / 256, 256, 0, stream>>>(pos, X, Y, Z, N);

    // K1: one wave per row -> N/4 blocks of 256.
    k1_pad_count<<<N / 4, 256, 0, stream>>>(X, Y, Z, box, out, counts, masks, N, P);

    // K2: one wave per row -> N/4 blocks of 256.
    k2_scan_fill<<<N / 4, 256, 0, stream>>>(X, Y, Z, box, counts, masks, out, N, P);
}